// Round 18
// baseline (71.287 us; speedup 1.0000x reference)
//
#include <hip/hip_runtime.h>
#include <math.h>

#define NXv 128
#define NYv 128
#define NZv 128
#define NVOX (NXv * NYv * NZv)
#define RPB  16    // rays per block (16 rays x 8 subs = 128 threads)
#define NSUB 8     // segment sub-ranges per ray
#define TSEG 63    // segments per LDS tile (loads TSEG+1 = 64 t-values/ray)

// Lane-per-ray tiled kernel + reg-prefetch + float2 volume + oversubscribed
// grid + NARROW (128-thread) blocks (R18).
//  * tvals bits are AUTHORITATIVE (R6): must be read, not recomputed.
//  * lane = ray (R7, 142->93us); LDS transpose tile stride 65.
//  * reg-prefetch of next tile before compute (R8, 93->84us).
//  * float2-interleaved volume in d_ws (R12, 84->82us).
//  * RPB 64->32, grid 4096 (R14, 82->64us): tail refill.
//  * Exhausted: R9/R11/R16 widening (VGPR/extra work), R10 lane-mixing,
//    R13 XCD swizzle (neutral), R15 finer rays @256thr (neutral),
//    R17 double-buffer (67.6us: occupancy 73% yet SLOWER -> more waves
//    raise gather latency; MLP/cache-pressure equilibrium).
//  * R18: isolate barrier-convoy width. 128-thread blocks (RPB=16, NSUB=8):
//    per-tile syncthreads_count convoys 2 waves instead of 4; 16
//    independent blocks/CU for scheduler mixing; early-exit granularity 16
//    rays. Per-thread compute structure identical to R14.
//
// NUMERICS (hard-won, rounds 1-17): x-segment midpoints land EXACTLY on
// floor() discontinuities. Golden ref is f32 numpy, SEPARATE mul-then-add.
// hipcc contracts a+tm*d into FMA -> absmax ~18.7 (threshold 1.25); __f*_rn
// are contractible (R2 == R1 bitwise); f64 mismatches (R3); recomputed t
// mismatches (R6). The asm VGPR pin on the product tm*d is what works
// (R4/R5/R7/R8/R10-R17 passed). Do not remove. Keep contract(off).

__global__ __launch_bounds__(256) void interleave2(
    const float* __restrict__ vol, float2* __restrict__ wsv, int nvox)
{
    int i = blockIdx.x * blockDim.x + threadIdx.x;
    const int stride = gridDim.x * blockDim.x;
    for (; i < nvox; i += stride)
        wsv[i] = make_float2(vol[i], vol[nvox + i]);
}

// F2=1: gather from interleaved float2 ws volume (BT must be 2).
// F2=0: gather from the original b-major volume (any BT).
template <int BT, int F2>
__global__ __launch_bounds__(128) void ct_pipe(
    const float* __restrict__ vol,    // (B, NX, NY, NZ)
    const float2* __restrict__ wsv,   // interleaved (NVOX) float2, if F2
    const float* __restrict__ tvals,  // (R, S) sorted, +inf padded
    const float* __restrict__ Mm,     // (3,3)
    const float* __restrict__ bb,     // (3,)
    const float* __restrict__ src,    // (R,3)
    const float* __restrict__ dst,    // (R,3)
    float* __restrict__ out,          // (B, R)
    int R, int S)
{
#pragma clang fp contract(off)
    __shared__ float tile[RPB][TSEG + 2];     // 16 x 65
    __shared__ float red[NSUB][RPB][2];       // cross-sub reduction

    const float INF = __builtin_inff();
    const int t    = threadIdx.x;
    const int rr   = t & (RPB - 1);   // compute role: ray within block (0..15)
    const int sub  = t >> 4;          // compute role: segment sub-range (0..7)
    const int w    = t >> 6;          // wave index (0..1), for load mapping
    const int lane = t & 63;          // lane within wave, for load mapping
    const int r0   = blockIdx.x * RPB;
    const int r    = r0 + rr;
    const bool active = (r < R);

    // --- per-ray geometry (verified R4/R5/R7/R8) ---
    float ax = 0, ay = 0, az = 0, dxx = 0, dyy = 0, dzz = 0, raylen = 0;
    if (active) {
        const float sx = src[r * 3 + 0], sy = src[r * 3 + 1], sz = src[r * 3 + 2];
        const float ex = dst[r * 3 + 0], ey = dst[r * 3 + 1], ez = dst[r * 3 + 2];
        const float M00 = Mm[0], M01 = Mm[1], M02 = Mm[2];
        const float M10 = Mm[3], M11 = Mm[4], M12 = Mm[5];
        const float M20 = Mm[6], M21 = Mm[7], M22 = Mm[8];
        ax = M00 * sx + M01 * sy + M02 * sz + bb[0];
        ay = M10 * sx + M11 * sy + M12 * sz + bb[1];
        az = M20 * sx + M21 * sy + M22 * sz + bb[2];
        const float vx = ex - sx, vy = ey - sy, vz = ez - sz;
        dxx = M00 * vx + M01 * vy + M02 * vz;
        dyy = M10 * vx + M11 * vy + M12 * vz;
        dzz = M20 * vx + M21 * vy + M22 * vz;
        raylen = sqrtf(vx * vx + vy * vy + vz * vz);
    }

    const int nseg  = S - 1;
    const int ntile = (nseg + TSEG - 1) / TSEG;
    float acc0 = 0.0f, acc1 = 0.0f;

    // staged registers: pf[p] = tvals[ray = r0 + 2p + w][s0 + lane]
    // (wave reads 64 consecutive t-values of one ray per pass -> coalesced;
    //  2 waves x 8 passes cover the 16 rays)
    float pf[8];
#pragma unroll
    for (int p = 0; p < 8; ++p) {
        const int ray = r0 + p * 2 + w;
        pf[p] = (ray < R && lane < S) ? tvals[(long)ray * S + lane] : INF;
    }

    for (int tl = 0; tl < ntile; ++tl) {
        // --- stage-write: regs -> LDS (compiler inserts the vmcnt wait) ---
#pragma unroll
        for (int p = 0; p < 8; ++p)
            tile[p * 2 + w][lane] = pf[p];

        // alive predicate from staged regs: lane-0 threads (w=0..1) hold the
        // tile-start values of rays p*2+w -> union covers all 16 rays.
        // Sorted + INF tail -> block-uniform break. The syncthreads_count
        // doubles as the write->read barrier (2-wave convoy only).
        bool pred = false;
        if (lane == 0) {
#pragma unroll
            for (int p = 0; p < 8; ++p) pred |= (pf[p] < INF);
        }
        const int alive = __syncthreads_count(pred);
        if (alive == 0) break;

        // --- prefetch next tile into regs (issued; consumed next iter) ---
        if (tl + 1 < ntile) {
            const int idx = (tl + 1) * TSEG + lane;
#pragma unroll
            for (int p = 0; p < 8; ++p) {
                const int ray = r0 + p * 2 + w;
                pf[p] = (ray < R && idx < S) ? tvals[(long)ray * S + idx] : INF;
            }
        }

        // --- compute: thread (rr,sub) owns cols [8*sub, 8*sub+8), fully
        //     unrolled branchy form (R16 lesson: exec-mask skip is a win) ---
        if (active) {
#pragma unroll
            for (int j = 0; j < 8; ++j) {
                const int c = 8 * sub + j;
                if (c < TSEG) {
                    const float t0 = tile[rr][c];
                    const float t1 = tile[rr][c + 1];
                    if ((t0 < INF) && (t1 < INF) && (t1 > t0)) {
                        // tmid=0.5*(t0+t1); pts=a+tmid*d — separate f32
                        // roundings, NO FMA: asm pins the product.
                        const float tm = 0.5f * (t0 + t1);
                        float mx = tm * dxx; asm volatile("" : "+v"(mx));
                        float my = tm * dyy; asm volatile("" : "+v"(my));
                        float mz = tm * dzz; asm volatile("" : "+v"(mz));
                        const float px = ax + mx;
                        const float py = ay + my;
                        const float pz = az + mz;
                        const int ix = (int)floorf(px);
                        const int iy = (int)floorf(py);
                        const int iz = (int)floorf(pz);
                        if ((unsigned)ix < NXv && (unsigned)iy < NYv && (unsigned)iz < NZv) {
                            const float w_ = (t1 - t0) * raylen;
                            const int flat = ((ix * NYv) + iy) * NZv + iz;
                            if (F2) {
                                const float2 g = wsv[flat];   // one dwordx2
                                acc0 += w_ * g.x;
                                acc1 += w_ * g.y;
                            } else {
                                acc0 += w_ * vol[flat];
                                if (BT > 1) acc1 += w_ * vol[NVOX + flat];
                            }
                        }
                    }
                }
            }
        }
        __syncthreads();   // tile consumed; next iter may overwrite
    }

    // --- deterministic cross-sub reduction + coalesced write ---
    red[sub][rr][0] = acc0;
    red[sub][rr][1] = (BT > 1) ? acc1 : 0.0f;
    __syncthreads();
    if (sub == 0 && active) {
        float s0v = 0.0f, s1v = 0.0f;
#pragma unroll
        for (int p = 0; p < NSUB; ++p) s0v += red[p][rr][0];
        out[r] = s0v;
        if (BT > 1) {
#pragma unroll
            for (int p = 0; p < NSUB; ++p) s1v += red[p][rr][1];
            out[R + r] = s1v;
        }
    }
}

extern "C" void kernel_launch(void* const* d_in, const int* in_sizes, int n_in,
                              void* d_out, int out_size, void* d_ws, size_t ws_size,
                              hipStream_t stream) {
    const float* vol   = (const float*)d_in[0];
    const float* tvals = (const float*)d_in[1];
    const float* Mm    = (const float*)d_in[2];
    const float* bb    = (const float*)d_in[3];
    const float* src   = (const float*)d_in[4];
    const float* dst   = (const float*)d_in[5];
    float* out = (float*)d_out;

    const int R = in_sizes[5] / 3;          // rays
    const int S = in_sizes[1] / R;          // t-values per ray
    const int B = in_sizes[0] / NVOX;       // batch of volumes

    const int blocks = (R + RPB - 1) / RPB; // 8192 for R=131072
    dim3 grid(blocks), block(RPB * NSUB);   // 128 threads

    const size_t need = (size_t)NVOX * sizeof(float2);

    if (B == 2 && ws_size >= need) {
        // one-time interleave: ws[i] = (vol0[i], vol1[i])
        float2* wsv = (float2*)d_ws;
        interleave2<<<2048, 256, 0, stream>>>(vol, wsv, NVOX);
        ct_pipe<2, 1><<<grid, block, 0, stream>>>(vol, wsv, tvals, Mm, bb, src, dst, out, R, S);
    } else if (B == 2) {
        ct_pipe<2, 0><<<grid, block, 0, stream>>>(vol, nullptr, tvals, Mm, bb, src, dst, out, R, S);
    } else if (B == 1) {
        ct_pipe<1, 0><<<grid, block, 0, stream>>>(vol, nullptr, tvals, Mm, bb, src, dst, out, R, S);
    } else {
        int c = 0;
        for (; c + 2 <= B; c += 2)
            ct_pipe<2, 0><<<grid, block, 0, stream>>>(vol + (long)c * NVOX, nullptr, tvals, Mm, bb,
                                                      src, dst, out + (long)c * R, R, S);
        for (; c < B; ++c)
            ct_pipe<1, 0><<<grid, block, 0, stream>>>(vol + (long)c * NVOX, nullptr, tvals, Mm, bb,
                                                      src, dst, out + (long)c * R, R, S);
    }
}

// Round 19
// 64.333 us; speedup vs baseline: 1.1081x; 1.1081x over previous
//
#include <hip/hip_runtime.h>
#include <math.h>

#define NXv 128
#define NYv 128
#define NZv 128
#define NVOX (NXv * NYv * NZv)
#define RPB  32    // rays per block (32 rays x 8 subs = 256 threads)
#define NSUB 8     // segment sub-ranges per ray
#define TSEG 63    // segments per LDS tile (loads TSEG+1 = 64 t-values/ray)

// R19 = exact revert to R14, the measured optimum (64.2us).
//  * tvals bits are AUTHORITATIVE (R6): must be read, not recomputed.
//  * lane = ray (R7, 142->93us): gathers span few cache lines, not 64.
//  * tvals coalescing via LDS transpose tile, stride 65 -> conflict-free.
//  * reg-prefetch of next tile before compute (R8, 93->84us).
//  * float2-interleaved volume in d_ws (R12, 84->82us): 1 gather/segment.
//  * RPB 64->32, grid 4096 = 2 rounds (R14, 82->64us): tail refill.
//  * PROVEN-NEGATIVE levers (do not retry): R9/R11 gather batching (VGPR
//    kills TLP), R10 lane-mixing, R13 XCD swizzle (neutral), R15 finer
//    refill (neutral), R16 branch-free gathers (-14%: exec-mask skip of
//    invalid slots is a win), R17 double-buffer (-5%: occupancy 73% yet
//    slower -> more waves raise gather latency), R18 narrow blocks (-11%,
//    + bank conflicts). The kernel sits at the MLP x gather-latency
//    equilibrium; ~64us is the structural floor of this algorithm.
//
// NUMERICS (hard-won, rounds 1-18): x-segment midpoints land EXACTLY on
// floor() discontinuities. Golden ref is f32 numpy, SEPARATE mul-then-add.
// hipcc contracts a+tm*d into FMA -> absmax ~18.7 (threshold 1.25); __f*_rn
// are contractible (R2 == R1 bitwise); f64 mismatches (R3); recomputed t
// mismatches (R6). The asm VGPR pin on the product tm*d is what works
// (R4/R5/R7/R8/R10-R18 passed). Do not remove. Keep contract(off).

__global__ __launch_bounds__(256) void interleave2(
    const float* __restrict__ vol, float2* __restrict__ wsv, int nvox)
{
    int i = blockIdx.x * blockDim.x + threadIdx.x;
    const int stride = gridDim.x * blockDim.x;
    for (; i < nvox; i += stride)
        wsv[i] = make_float2(vol[i], vol[nvox + i]);
}

// F2=1: gather from interleaved float2 ws volume (BT must be 2).
// F2=0: gather from the original b-major volume (any BT).
template <int BT, int F2>
__global__ __launch_bounds__(256) void ct_pipe(
    const float* __restrict__ vol,    // (B, NX, NY, NZ)
    const float2* __restrict__ wsv,   // interleaved (NVOX) float2, if F2
    const float* __restrict__ tvals,  // (R, S) sorted, +inf padded
    const float* __restrict__ Mm,     // (3,3)
    const float* __restrict__ bb,     // (3,)
    const float* __restrict__ src,    // (R,3)
    const float* __restrict__ dst,    // (R,3)
    float* __restrict__ out,          // (B, R)
    int R, int S)
{
#pragma clang fp contract(off)
    __shared__ float tile[RPB][TSEG + 2];     // 32 x 65: stride 65 -> conflict-free
    __shared__ float red[NSUB][RPB][2];       // cross-sub reduction

    const float INF = __builtin_inff();
    const int t    = threadIdx.x;
    const int rr   = t & (RPB - 1);   // compute role: ray within block (0..31)
    const int sub  = t >> 5;          // compute role: segment sub-range (0..7)
    const int w    = t >> 6;          // wave index (0..3), for load mapping
    const int lane = t & 63;          // lane within wave, for load mapping
    const int r0   = blockIdx.x * RPB;
    const int r    = r0 + rr;
    const bool active = (r < R);

    // --- per-ray geometry (verified R4/R5/R7/R8) ---
    float ax = 0, ay = 0, az = 0, dxx = 0, dyy = 0, dzz = 0, raylen = 0;
    if (active) {
        const float sx = src[r * 3 + 0], sy = src[r * 3 + 1], sz = src[r * 3 + 2];
        const float ex = dst[r * 3 + 0], ey = dst[r * 3 + 1], ez = dst[r * 3 + 2];
        const float M00 = Mm[0], M01 = Mm[1], M02 = Mm[2];
        const float M10 = Mm[3], M11 = Mm[4], M12 = Mm[5];
        const float M20 = Mm[6], M21 = Mm[7], M22 = Mm[8];
        ax = M00 * sx + M01 * sy + M02 * sz + bb[0];
        ay = M10 * sx + M11 * sy + M12 * sz + bb[1];
        az = M20 * sx + M21 * sy + M22 * sz + bb[2];
        const float vx = ex - sx, vy = ey - sy, vz = ez - sz;
        dxx = M00 * vx + M01 * vy + M02 * vz;
        dyy = M10 * vx + M11 * vy + M12 * vz;
        dzz = M20 * vx + M21 * vy + M22 * vz;
        raylen = sqrtf(vx * vx + vy * vy + vz * vz);
    }

    const int nseg  = S - 1;
    const int ntile = (nseg + TSEG - 1) / TSEG;
    float acc0 = 0.0f, acc1 = 0.0f;

    // staged registers: pf[p] = tvals[ray = r0 + 4p + w][s0 + lane]
    // (wave reads 64 consecutive t-values of one ray per pass -> coalesced)
    float pf[8];
    {
#pragma unroll
        for (int p = 0; p < 8; ++p) {
            const int ray = r0 + p * 4 + w;
            pf[p] = (ray < R && lane < S) ? tvals[(long)ray * S + lane] : INF;
        }
    }

    for (int tl = 0; tl < ntile; ++tl) {
        // --- stage-write: regs -> LDS (compiler inserts the vmcnt wait) ---
#pragma unroll
        for (int p = 0; p < 8; ++p)
            tile[p * 4 + w][lane] = pf[p];

        // alive predicate from staged regs: lane-0 threads (w=0..3) hold the
        // tile-start values of rays p*4+w -> union covers all 32 rays.
        // Sorted + INF tail -> block-uniform break. The syncthreads_count
        // doubles as the write->read barrier.
        bool pred = false;
        if (lane == 0) {
#pragma unroll
            for (int p = 0; p < 8; ++p) pred |= (pf[p] < INF);
        }
        const int alive = __syncthreads_count(pred);
        if (alive == 0) break;

        // --- prefetch next tile into regs (issued; consumed next iter) ---
        if (tl + 1 < ntile) {
            const int idx = (tl + 1) * TSEG + lane;
#pragma unroll
            for (int p = 0; p < 8; ++p) {
                const int ray = r0 + p * 4 + w;
                pf[p] = (ray < R && idx < S) ? tvals[(long)ray * S + idx] : INF;
            }
        }

        // --- compute: thread (rr,sub) owns cols [8*sub, 8*sub+8), fully
        //     unrolled branchy form (R16 lesson: exec-mask skip is a win) ---
        if (active) {
#pragma unroll
            for (int j = 0; j < 8; ++j) {
                const int c = 8 * sub + j;
                if (c < TSEG) {
                    const float t0 = tile[rr][c];
                    const float t1 = tile[rr][c + 1];
                    if ((t0 < INF) && (t1 < INF) && (t1 > t0)) {
                        // tmid=0.5*(t0+t1); pts=a+tmid*d — separate f32
                        // roundings, NO FMA: asm pins the product.
                        const float tm = 0.5f * (t0 + t1);
                        float mx = tm * dxx; asm volatile("" : "+v"(mx));
                        float my = tm * dyy; asm volatile("" : "+v"(my));
                        float mz = tm * dzz; asm volatile("" : "+v"(mz));
                        const float px = ax + mx;
                        const float py = ay + my;
                        const float pz = az + mz;
                        const int ix = (int)floorf(px);
                        const int iy = (int)floorf(py);
                        const int iz = (int)floorf(pz);
                        if ((unsigned)ix < NXv && (unsigned)iy < NYv && (unsigned)iz < NZv) {
                            const float w_ = (t1 - t0) * raylen;
                            const int flat = ((ix * NYv) + iy) * NZv + iz;
                            if (F2) {
                                const float2 g = wsv[flat];   // one dwordx2
                                acc0 += w_ * g.x;
                                acc1 += w_ * g.y;
                            } else {
                                acc0 += w_ * vol[flat];
                                if (BT > 1) acc1 += w_ * vol[NVOX + flat];
                            }
                        }
                    }
                }
            }
        }
        __syncthreads();   // tile consumed; next iter may overwrite
    }

    // --- deterministic cross-sub reduction + coalesced write ---
    red[sub][rr][0] = acc0;
    red[sub][rr][1] = (BT > 1) ? acc1 : 0.0f;
    __syncthreads();
    if (sub == 0 && active) {
        float s0v = 0.0f, s1v = 0.0f;
#pragma unroll
        for (int p = 0; p < NSUB; ++p) s0v += red[p][rr][0];
        out[r] = s0v;
        if (BT > 1) {
#pragma unroll
            for (int p = 0; p < NSUB; ++p) s1v += red[p][rr][1];
            out[R + r] = s1v;
        }
    }
}

extern "C" void kernel_launch(void* const* d_in, const int* in_sizes, int n_in,
                              void* d_out, int out_size, void* d_ws, size_t ws_size,
                              hipStream_t stream) {
    const float* vol   = (const float*)d_in[0];
    const float* tvals = (const float*)d_in[1];
    const float* Mm    = (const float*)d_in[2];
    const float* bb    = (const float*)d_in[3];
    const float* src   = (const float*)d_in[4];
    const float* dst   = (const float*)d_in[5];
    float* out = (float*)d_out;

    const int R = in_sizes[5] / 3;          // rays
    const int S = in_sizes[1] / R;          // t-values per ray
    const int B = in_sizes[0] / NVOX;       // batch of volumes

    const int blocks = (R + RPB - 1) / RPB; // 4096 for R=131072
    dim3 grid(blocks), block(RPB * NSUB);   // 256 threads

    const size_t need = (size_t)NVOX * sizeof(float2);

    if (B == 2 && ws_size >= need) {
        // one-time interleave: ws[i] = (vol0[i], vol1[i])
        float2* wsv = (float2*)d_ws;
        interleave2<<<2048, 256, 0, stream>>>(vol, wsv, NVOX);
        ct_pipe<2, 1><<<grid, block, 0, stream>>>(vol, wsv, tvals, Mm, bb, src, dst, out, R, S);
    } else if (B == 2) {
        ct_pipe<2, 0><<<grid, block, 0, stream>>>(vol, nullptr, tvals, Mm, bb, src, dst, out, R, S);
    } else if (B == 1) {
        ct_pipe<1, 0><<<grid, block, 0, stream>>>(vol, nullptr, tvals, Mm, bb, src, dst, out, R, S);
    } else {
        int c = 0;
        for (; c + 2 <= B; c += 2)
            ct_pipe<2, 0><<<grid, block, 0, stream>>>(vol + (long)c * NVOX, nullptr, tvals, Mm, bb,
                                                      src, dst, out + (long)c * R, R, S);
        for (; c < B; ++c)
            ct_pipe<1, 0><<<grid, block, 0, stream>>>(vol + (long)c * NVOX, nullptr, tvals, Mm, bb,
                                                      src, dst, out + (long)c * R, R, S);
    }
}